// Round 14
// baseline (221.056 us; speedup 1.0000x reference)
//
#include <hip/hip_runtime.h>
#include <hip/hip_bf16.h>
#include <math.h>

#define BB 4
#define TT 2048
#define CC 768
#define NHD 16
#define HD 48
#define NQT2 16  // TT/128

typedef __hip_bfloat16 bf16;
typedef __attribute__((ext_vector_type(8))) short short8;
typedef __attribute__((ext_vector_type(4))) float floatx4;

__device__ __forceinline__ unsigned short f2bf(float x) {
    bf16 h = __float2bfloat16(x);
    return *(unsigned short*)&h;
}
__device__ __forceinline__ float bfu2f(unsigned short u) {
    return __uint_as_float(((unsigned)u) << 16);
}

// async global->LDS, 16B per lane; LDS dest = wave-uniform base + lane*16
__device__ __forceinline__ void gl_lds16(const void* g, void* s) {
    __builtin_amdgcn_global_load_lds((const __attribute__((address_space(1))) void*)g,
                                     (__attribute__((address_space(3))) void*)s, 16, 0, 0);
}

// pack two fp32 -> packed bf16 pair (round-half-up; inputs are probabilities >= 0)
__device__ __forceinline__ unsigned int pk_bf2(float a, float b) {
    unsigned int ua = __float_as_uint(a) + 0x8000u;
    unsigned int ub = __float_as_uint(b) + 0x8000u;
    return __builtin_amdgcn_perm(ub, ua, 0x07060302);
}

// hot-loop barrier: make LDS writes visible, do NOT drain vmcnt -- register
// global loads (K/V prefetch) stay in flight across the barrier.
#define HOT_BARRIER() asm volatile("s_waitcnt lgkmcnt(0)\n\ts_barrier" ::: "memory")

// ---------- fused setup: hs cast + 4 weight casts + RoPE table, ONE launch ----------
// The three setup kernels are independent (disjoint outputs, no ordering
// among them); merging removes 2 launch boundaries (~10us each for short
// dispatches) and lets the small parts run concurrently with the big cast.
// Per-thread indexing of each part is verbatim from the split kernels.
__global__ __launch_bounds__(256) void setup_all(const float* __restrict__ hs,
                                                 unsigned short* __restrict__ hb,
                                                 const float* __restrict__ Wq, const float* __restrict__ Wk,
                                                 const float* __restrict__ Wv, const float* __restrict__ Wo,
                                                 unsigned short* __restrict__ wqb, unsigned short* __restrict__ wkb,
                                                 unsigned short* __restrict__ wvb, unsigned short* __restrict__ wob,
                                                 float2* __restrict__ tab) {
    const int bx = blockIdx.x;
    const int tid = threadIdx.x;
    if (bx < 6144) {                     // cast_hs: 6144*1024 = 6291456 elems
        size_t i = (size_t)bx * 1024 + tid * 4;
        float4 v = *(const float4*)(hs + i);
        ushort4 p;
        p.x = f2bf(v.x); p.y = f2bf(v.y); p.z = f2bf(v.z); p.w = f2bf(v.w);
        *(ushort4*)(hb + i) = p;
    } else if (bx < 8448) {              // cast_w4: 4 x 576 blocks
        int u = bx - 6144;
        const float* s; unsigned short* d;
        switch (u / 576) {
            case 0: s = Wq; d = wqb; break;
            case 1: s = Wk; d = wkb; break;
            case 2: s = Wv; d = wvb; break;
            default: s = Wo; d = wob; break;
        }
        size_t i = (size_t)(u % 576) * 1024 + tid * 4;
        float4 v = *(const float4*)(s + i);
        ushort4 p;
        p.x = f2bf(v.x); p.y = f2bf(v.y); p.z = f2bf(v.z); p.w = f2bf(v.w);
        *(ushort4*)(d + i) = p;
    } else {                             // rope_table: 192*256 = 49152 = 2048*24
        int idx = (bx - 8448) * 256 + tid;
        int t = idx / 24, p = idx % 24;
        float inv_freq = powf(10000.0f, -((float)(2 * p) / (float)HD));
        float ang = (float)t * inv_freq;
        float sn, cs;
        sincosf(ang, &sn, &cs);
        tab[idx] = make_float2(cs, sn);
    }
}

// ---------- bf16 MFMA NT-GEMM, BK=64, lds-direct staging with XOR-swizzle ----------
// MODE 1 only now: fused QKV N=2304 (NXB=18).
template <int MODE>
__global__ __launch_bounds__(256) void gemm_mfma(const unsigned short* __restrict__ A,
                                                 const unsigned short* __restrict__ Bw,
                                                 const float* __restrict__ b0p,
                                                 const float* __restrict__ b1p,
                                                 const float* __restrict__ b2p,
                                                 void* __restrict__ out0,
                                                 void* __restrict__ out1,
                                                 void* __restrict__ out2) {
    __shared__ __align__(16) unsigned short As[128][64];
    __shared__ __align__(16) unsigned short Bs[128][64];
    const int tid = threadIdx.x;
    const int w = tid >> 6, lane = tid & 63;
    const int quad = lane >> 4, ln = lane & 15;
    const int wr = w >> 1, wc = w & 1;

    const int NXB = (MODE == 1) ? 18 : 6;
    const int bx = blockIdx.x;
    const int xcd = bx & 7, slot = bx >> 3;
    const int n0 = (slot % NXB) * 128;
    const int m0 = ((slot / NXB) * 8 + xcd) * 128;

    const int srow = lane >> 3;
    const int ssw = ((lane & 7) ^ srow) * 8;
    const unsigned short* agp[4];
    const unsigned short* bgp[4];
    void* asl[4];
    void* bsl[4];
#pragma unroll
    for (int i = 0; i < 4; ++i) {
        const int R = i * 32 + w * 8;
        agp[i] = A + (size_t)(m0 + R + srow) * CC + ssw;
        bgp[i] = Bw + (size_t)(n0 + R + srow) * CC + ssw;
        asl[i] = &As[R][0];
        bsl[i] = &Bs[R][0];
    }

    floatx4 acc[4][4];
#pragma unroll
    for (int mi = 0; mi < 4; ++mi)
#pragma unroll
        for (int ni = 0; ni < 4; ++ni) acc[mi][ni] = (floatx4){0.f, 0.f, 0.f, 0.f};

    const int ps0 = (quad ^ (ln & 7)) * 8;

    for (int k0 = 0; k0 < CC; k0 += 64) {
        __syncthreads();
#pragma unroll
        for (int i = 0; i < 4; ++i) {
            gl_lds16(agp[i] + k0, asl[i]);
            gl_lds16(bgp[i] + k0, bsl[i]);
        }
        __syncthreads();
#pragma unroll
        for (int kh = 0; kh < 2; ++kh) {
            const int ps = ps0 ^ (kh * 32);
            short8 af[4], bfr[4];
#pragma unroll
            for (int mi = 0; mi < 4; ++mi)
                af[mi] = *(const short8*)&As[wr * 64 + mi * 16 + ln][ps];
#pragma unroll
            for (int ni = 0; ni < 4; ++ni)
                bfr[ni] = *(const short8*)&Bs[wc * 64 + ni * 16 + ln][ps];
#pragma unroll
            for (int mi = 0; mi < 4; ++mi)
#pragma unroll
                for (int ni = 0; ni < 4; ++ni)
                    acc[mi][ni] = __builtin_amdgcn_mfma_f32_16x16x32_bf16(af[mi], bfr[ni], acc[mi][ni], 0, 0, 0);
        }
    }

    {
        const int seg = n0 / CC;
        const int nl0 = n0 - seg * CC;
        const float* bp = (seg == 0) ? b0p : (seg == 1) ? b1p : b2p;
        float bv[4];
#pragma unroll
        for (int ni = 0; ni < 4; ++ni) bv[ni] = bp[nl0 + wc * 64 + ni * 16 + ln];

        if (seg < 2) {
            unsigned short* outb = (unsigned short*)(seg == 0 ? out0 : out1);
#pragma unroll
            for (int mi = 0; mi < 4; ++mi)
#pragma unroll
                for (int r = 0; r < 4; ++r) {
                    size_t row = m0 + wr * 64 + mi * 16 + quad * 4 + r;
#pragma unroll
                    for (int ni = 0; ni < 4; ++ni)
                        outb[row * CC + nl0 + wc * 64 + ni * 16 + ln] = f2bf(acc[mi][ni][r] + bv[ni]);
                }
        } else {
            unsigned short* outb = (unsigned short*)out2;
            const int b = m0 >> 11;
#pragma unroll
            for (int ni = 0; ni < 4; ++ni) {
                int col = nl0 + wc * 64 + ni * 16 + ln;
                int h = col / HD, d = col % HD;
                size_t base = (size_t)((b * NHD + h) * HD + d) * TT;
#pragma unroll
                for (int mi = 0; mi < 4; ++mi) {
                    int t = (m0 & 2047) + wr * 64 + mi * 16 + quad * 4;
                    ushort4 pk;
                    pk.x = f2bf(acc[mi][ni][0] + bv[ni]);
                    pk.y = f2bf(acc[mi][ni][1] + bv[ni]);
                    pk.z = f2bf(acc[mi][ni][2] + bv[ni]);
                    pk.w = f2bf(acc[mi][ni][3] + bv[ni]);
                    *(ushort4*)(outb + base + t) = pk;
                }
            }
        }
    }
}

// ---------- output projection GEMM: 128x64 tiles, grid 768 = 3.0 blocks/CU ----------
__global__ __launch_bounds__(256) void gemm_out(const unsigned short* __restrict__ A,
                                                const unsigned short* __restrict__ Bw,
                                                const float* __restrict__ bias,
                                                float* __restrict__ out) {
    __shared__ __align__(16) unsigned short As[128][64];
    __shared__ __align__(16) unsigned short Bs[64][64];
    const int tid = threadIdx.x;
    const int w = tid >> 6, lane = tid & 63;
    const int quad = lane >> 4, ln = lane & 15;

    const int bx = blockIdx.x;
    const int xcd = bx & 7, slot = bx >> 3;      // slot in [0,96)
    const int n0 = (slot % 12) * 64;
    const int m0 = ((slot / 12) * 8 + xcd) * 128;

    const int srow = lane >> 3;
    const int ssw = ((lane & 7) ^ srow) * 8;
    const unsigned short* agp[4];
    const unsigned short* bgp[2];
    void* asl[4];
    void* bsl[2];
#pragma unroll
    for (int i = 0; i < 4; ++i) {
        const int R = i * 32 + w * 8;            // rows 0..127 w/ srow
        agp[i] = A + (size_t)(m0 + R + srow) * CC + ssw;
        asl[i] = &As[R][0];
    }
#pragma unroll
    for (int i = 0; i < 2; ++i) {
        const int R = i * 32 + w * 8;            // rows 0..63 w/ srow
        bgp[i] = Bw + (size_t)(n0 + R + srow) * CC + ssw;
        bsl[i] = &Bs[R][0];
    }

    floatx4 acc[2][4];
#pragma unroll
    for (int mi = 0; mi < 2; ++mi)
#pragma unroll
        for (int ni = 0; ni < 4; ++ni) acc[mi][ni] = (floatx4){0.f, 0.f, 0.f, 0.f};

    const int ps0 = (quad ^ (ln & 7)) * 8;

    for (int k0 = 0; k0 < CC; k0 += 64) {
        __syncthreads();
#pragma unroll
        for (int i = 0; i < 4; ++i) gl_lds16(agp[i] + k0, asl[i]);
#pragma unroll
        for (int i = 0; i < 2; ++i) gl_lds16(bgp[i] + k0, bsl[i]);
        __syncthreads();
#pragma unroll
        for (int kh = 0; kh < 2; ++kh) {
            const int ps = ps0 ^ (kh * 32);
            short8 af[2], bfr[4];
#pragma unroll
            for (int mi = 0; mi < 2; ++mi)
                af[mi] = *(const short8*)&As[w * 32 + mi * 16 + ln][ps];
#pragma unroll
            for (int ni = 0; ni < 4; ++ni)
                bfr[ni] = *(const short8*)&Bs[ni * 16 + ln][ps];
#pragma unroll
            for (int mi = 0; mi < 2; ++mi)
#pragma unroll
                for (int ni = 0; ni < 4; ++ni)
                    acc[mi][ni] = __builtin_amdgcn_mfma_f32_16x16x32_bf16(af[mi], bfr[ni], acc[mi][ni], 0, 0, 0);
        }
    }

    float bv[4];
#pragma unroll
    for (int ni = 0; ni < 4; ++ni) bv[ni] = bias[n0 + ni * 16 + ln];
#pragma unroll
    for (int mi = 0; mi < 2; ++mi)
#pragma unroll
        for (int r = 0; r < 4; ++r) {
            size_t row = m0 + w * 32 + mi * 16 + quad * 4 + r;
#pragma unroll
            for (int ni = 0; ni < 4; ++ni)
                out[row * CC + n0 + ni * 16 + ln] = acc[mi][ni][r] + bv[ni];
        }
}

// RoPE in-place via precomputed table, vectorized (8 pairs/thread).
__global__ __launch_bounds__(256) void rope_bf(unsigned short* __restrict__ q,
                                               unsigned short* __restrict__ k,
                                               const float2* __restrict__ tab) {
    int idx = blockIdx.x * blockDim.x + threadIdx.x;  // over B*T*H*3
    const int HALF = HD / 2;
    int p8 = idx % 3;
    int rest = idx / 3;
    int h = rest % NHD;
    int n = rest / NHD;        // b*T + t
    int t = n & (TT - 1);
    const float QSC = 0.14433756729740643f * 1.4426950408889634f;
    size_t base = (size_t)n * CC + h * HD + p8 * 8;
    const float2* tp = tab + t * HALF + p8 * 8;

    short8 q1 = *(const short8*)(q + base);
    short8 q2 = *(const short8*)(q + base + HALF);
    short8 k1 = *(const short8*)(k + base);
    short8 k2 = *(const short8*)(k + base + HALF);
    short8 r1, r2, s1, s2;
#pragma unroll
    for (int jj = 0; jj < 8; ++jj) {
        float2 cssn = tp[jj];
        float cs = cssn.x, sn = cssn.y;
        float a = bfu2f((unsigned short)q1[jj]), bb = bfu2f((unsigned short)q2[jj]);
        r1[jj] = (short)f2bf((a * cs - bb * sn) * QSC);
        r2[jj] = (short)f2bf((bb * cs + a * sn) * QSC);
        float c2 = bfu2f((unsigned short)k1[jj]), d2 = bfu2f((unsigned short)k2[jj]);
        s1[jj] = (short)f2bf(c2 * cs - d2 * sn);
        s2[jj] = (short)f2bf(d2 * cs + c2 * sn);
    }
    *(short8*)(q + base) = r1;
    *(short8*)(q + base + HALF) = r2;
    *(short8*)(k + base) = s1;
    *(short8*)(k + base + HALF) = s2;
}

// MFMA flash attention, exp2-domain, fixed softmax reference (m=0).
// Harness-verified session best (round 4/11/12, ~55us): 128 q-rows per
// block (two 64-row groups a/b per wave: each wave owns 32 q-rows), so every
// K/V fragment read from LDS feeds TWO MFMAs. K and V live in LDS
// (XOR-swizzled, [64] cols); both barriers are lgkm-only so the K/V register
// prefetch stays in flight. Q direct from global. Grid 512 = 64 (b,h) x 8
// pairs; pair schedule (qt, 15-qt) = exactly 34 k-steps per block;
// XCD-pinned -> exactly 2 blocks/CU, zero tail. launch_bounds(256,2):
// 256-VGPR cap eliminates the spill failure mode.
__global__ __launch_bounds__(256, 2) void attn_kernel(const unsigned short* __restrict__ qb,
                                                      const unsigned short* __restrict__ kb,
                                                      const unsigned short* __restrict__ vt,
                                                      const float* __restrict__ amask,
                                                      unsigned short* __restrict__ ctx) {
    const int bx = blockIdx.x;
    const int xcd = bx & 7;
    const int rem = bx >> 3;                // [0,64)
    const int pair = rem & 7;
    const int j = ((rem >> 3) << 3) | xcd;  // (b,h) group, grouped per XCD
    const int b = j >> 4, h = j & 15;
    const int tid = threadIdx.x;
    const int w = tid >> 6, lane = tid & 63;
    const int g = lane >> 4, ln = lane & 15;
    const int sw = ln & 7;

    __shared__ __align__(16) unsigned short Ks[64][64];
    __shared__ __align__(16) unsigned short Vs[48][64];
    __shared__ __align__(16) unsigned short Pw[4][32][64];
    __shared__ __align__(16) float l_s[4][32];

    const short8 z8 = {0, 0, 0, 0, 0, 0, 0, 0};
    const short8 ones8 = {0x3F80, 0x3F80, 0x3F80, 0x3F80, 0x3F80, 0x3F80, 0x3F80, 0x3F80};

    // zero Ks pad units 6,7 (XOR-swizzled) once; unit-6 elem 0 = mask slot
    // (rewritten each step), elems 1..7 and unit 7 stay 0.
    if (tid < 128) {
        int rr = tid >> 1, half = tid & 1;
        *(short8*)&Ks[rr][((6 + half) ^ (rr & 7)) * 8] = z8;
    }

    // K stage: 64 rows x 6 units (48 cols). V stage: 48 rows x 8 units (64 cols).
    const int ck1 = tid + 256;
    const int rK0 = tid / 6, sK0 = tid % 6;
    const int rK1 = ck1 / 6, sK1 = ck1 % 6;
    const int swK0 = (sK0 ^ (rK0 & 7)) * 8;
    const int swK1 = (sK1 ^ (rK1 & 7)) * 8;
    const int rV0 = tid >> 3, sV0 = tid & 7;   // rows 0..31
    const int rV1 = rV0 + 32;                  // tid<128: rows 32..47
    const int swV0 = (sV0 ^ (rV0 & 7)) * 8;
    const int swV1 = (sV0 ^ (rV1 & 7)) * 8;

    const unsigned short* kbase0 = kb + (size_t)(b * TT + rK0) * CC + h * HD + sK0 * 8;
    const unsigned short* kbase1 = kb + (size_t)(b * TT + rK1) * CC + h * HD + sK1 * 8;
    const unsigned short* vbase0 = vt + ((size_t)((b * NHD + h) * HD) + rV0) * TT + sV0 * 8;
    const unsigned short* vbase1 = vbase0 + (size_t)32 * TT;
    const float* mbase = amask + b * TT + (tid & 63);
    const float MBS = -10000.0f * 1.4426950408889634f;
    const int mcol = (6 ^ (lane & 7)) * 8;     // swizzled mask slot (row = lane)
    const short8 vone = (ln == 0) ? ones8 : z8;  // ones-column B-frag (l accumulator)

    for (int rep = 0; rep < 2; ++rep) {
        const int qt = rep ? (NQT2 - 1 - pair) : pair;
        const int q0 = qt * 128;
        const int last = 2 * qt + 1;

        // Q fragments straight from global, two row-groups per wave.
        const unsigned short* qrA = qb + (size_t)(b * TT + q0 + w * 16 + ln) * CC + h * HD;
        const unsigned short* qrB = qrA + (size_t)64 * CC;
        short8 aq0a = *(const short8*)(qrA + g * 8);
        short8 aq0b = *(const short8*)(qrB + g * 8);
        short8 aq1a, aq1b;
        if (g < 2) {
            aq1a = *(const short8*)(qrA + 32 + g * 8);
            aq1b = *(const short8*)(qrB + 32 + g * 8);
        } else {
            aq1a = z8; aq1b = z8;
            if (g == 2) { aq1a[0] = (short)0x3F80; aq1b[0] = (short)0x3F80; }
        }

        const unsigned short* kp0 = kbase0;
        const unsigned short* kp1 = kbase1;
        const unsigned short* vp0 = vbase0;
        const unsigned short* vp1 = vbase1;
        const float* mp = mbase;

        short8 kr0, kr1, vr0, vr1;
        float mr = 1.0f;
        kr0 = *(const short8*)kp0;
        vr0 = *(const short8*)vp0;
        if (tid < 128) { kr1 = *(const short8*)kp1; vr1 = *(const short8*)vp1; }
        if (tid < 64) mr = *mp;

        const int qlA = q0 + w * 16 + ln;
        const int qlB = qlA + 64;
        floatx4 oa0 = {0.f, 0.f, 0.f, 0.f}, oa1 = oa0, oa2 = oa0, oa3 = oa0;
        floatx4 ob0 = oa0, ob1 = oa0, ob2 = oa0, ob3 = oa0;

        for (int kt = 0; kt <= last; ++kt) {
            HOT_BARRIER();   // prior step's LDS reads complete
            *(short8*)&Ks[rK0][swK0] = kr0;
            *(short8*)&Vs[rV0][swV0] = vr0;
            if (tid < 128) {
                *(short8*)&Ks[rK1][swK1] = kr1;
                *(short8*)&Vs[rV1][swV1] = vr1;
            }
            if (tid < 64) Ks[lane][mcol] = f2bf((1.0f - mr) * MBS);
            HOT_BARRIER();   // writes visible; vmcnt NOT drained

            if (kt < last) {
                kp0 += (size_t)64 * CC; kr0 = *(const short8*)kp0;
                vp0 += 64;              vr0 = *(const short8*)vp0;
                if (tid < 128) {
                    kp1 += (size_t)64 * CC; kr1 = *(const short8*)kp1;
                    vp1 += 64;              vr1 = *(const short8*)vp1;
                }
                if (tid < 64) { mp += 64; mr = *mp; }
            }

            const int k0 = kt * 64;
            const bool a_act = (kt <= 2 * qt);
            const bool diagA = (kt == 2 * qt);
            const bool diagB = (kt == last);

            // QK^T: each K fragment read feeds BOTH q-groups.
            floatx4 sa[4], sb[4];
#pragma unroll
            for (int c = 0; c < 4; ++c) {
                short8 kf0 = *(const short8*)&Ks[c * 16 + ln][(g ^ sw) * 8];
                short8 kf1 = *(const short8*)&Ks[c * 16 + ln][((4 + g) ^ sw) * 8];
                floatx4 z = {0.f, 0.f, 0.f, 0.f};
                if (a_act) {
                    floatx4 za = __builtin_amdgcn_mfma_f32_16x16x32_bf16(kf0, aq0a, z, 0, 0, 0);
                    sa[c] = __builtin_amdgcn_mfma_f32_16x16x32_bf16(kf1, aq1a, za, 0, 0, 0);
                }
                floatx4 zb = __builtin_amdgcn_mfma_f32_16x16x32_bf16(kf0, aq0b, z, 0, 0, 0);
                sb[c] = __builtin_amdgcn_mfma_f32_16x16x32_bf16(kf1, aq1b, zb, 0, 0, 0);
            }

            // softmax (exp2-domain) + pack into Pw; group a rows [ln], b rows [16+ln]
            if (a_act) {
#pragma unroll
                for (int c = 0; c < 4; ++c) {
                    float pv[4];
#pragma unroll
                    for (int r = 0; r < 4; ++r) {
                        float e = __builtin_amdgcn_exp2f(sa[c][r]);
                        if (diagA && (k0 + c * 16 + g * 4 + r > qlA)) e = 0.f;
                        pv[r] = e;
                    }
                    uint2 pk;
                    pk.x = pk_bf2(pv[0], pv[1]);
                    pk.y = pk_bf2(pv[2], pv[3]);
                    *(uint2*)&Pw[w][ln][((2 * c + (g >> 1)) ^ sw) * 8 + (g & 1) * 4] = pk;
                }
            }
#pragma unroll
            for (int c = 0; c < 4; ++c) {
                float pv[4];
#pragma unroll
                for (int r = 0; r < 4; ++r) {
                    float e = __builtin_amdgcn_exp2f(sb[c][r]);
                    if (diagB && (k0 + c * 16 + g * 4 + r > qlB)) e = 0.f;
                    pv[r] = e;
                }
                uint2 pk;
                pk.x = pk_bf2(pv[0], pv[1]);
                pk.y = pk_bf2(pv[2], pv[3]);
                *(uint2*)&Pw[w][16 + ln][((2 * c + (g >> 1)) ^ sw) * 8 + (g & 1) * 4] = pk;
            }

            short8 pa0a, pa1a;
            if (a_act) {
                pa0a = *(const short8*)&Pw[w][ln][(g ^ sw) * 8];
                pa1a = *(const short8*)&Pw[w][ln][((4 + g) ^ sw) * 8];
            }
            short8 pa0b = *(const short8*)&Pw[w][16 + ln][(g ^ sw) * 8];
            short8 pa1b = *(const short8*)&Pw[w][16 + ln][((4 + g) ^ sw) * 8];

            // PV: each V fragment read feeds BOTH q-groups.
#pragma unroll
            for (int n = 0; n < 3; ++n) {
                short8 vb0 = *(const short8*)&Vs[n * 16 + ln][(g ^ sw) * 8];
                short8 vb1 = *(const short8*)&Vs[n * 16 + ln][((4 + g) ^ sw) * 8];
                if (a_act) {
                    floatx4 acc = (n == 0) ? oa0 : (n == 1) ? oa1 : oa2;
                    acc = __builtin_amdgcn_mfma_f32_16x16x32_bf16(pa0a, vb0, acc, 0, 0, 0);
                    acc = __builtin_amdgcn_mfma_f32_16x16x32_bf16(pa1a, vb1, acc, 0, 0, 0);
                    if (n == 0) oa0 = acc; else if (n == 1) oa1 = acc; else oa2 = acc;
                }
                floatx4 accb = (n == 0) ? ob0 : (n == 1) ? ob1 : ob2;
                accb = __builtin_amdgcn_mfma_f32_16x16x32_bf16(pa0b, vb0, accb, 0, 0, 0);
                accb = __builtin_amdgcn_mfma_f32_16x16x32_bf16(pa1b, vb1, accb, 0, 0, 0);
                if (n == 0) ob0 = accb; else if (n == 1) ob1 = accb; else ob2 = accb;
            }
            if (a_act) {
                oa3 = __builtin_amdgcn_mfma_f32_16x16x32_bf16(pa0a, vone, oa3, 0, 0, 0);
                oa3 = __builtin_amdgcn_mfma_f32_16x16x32_bf16(pa1a, vone, oa3, 0, 0, 0);
            }
            ob3 = __builtin_amdgcn_mfma_f32_16x16x32_bf16(pa0b, vone, ob3, 0, 0, 0);
            ob3 = __builtin_amdgcn_mfma_f32_16x16x32_bf16(pa1b, vone, ob3, 0, 0, 0);
        }

        if (ln == 0) {
            *(floatx4*)&l_s[w][g * 4] = oa3;          // per-wave region, no barrier
            *(floatx4*)&l_s[w][16 + g * 4] = ob3;
        }
        floatx4 l4a = *(const floatx4*)&l_s[w][g * 4];
        floatx4 l4b = *(const floatx4*)&l_s[w][16 + g * 4];
#pragma unroll
        for (int r = 0; r < 4; ++r) {
            float invA = 1.0f / l4a[r];
            int t = q0 + w * 16 + g * 4 + r;
            unsigned short* dst = ctx + (size_t)(b * TT + t) * CC + h * HD;
            dst[ln] = f2bf(oa0[r] * invA);
            dst[16 + ln] = f2bf(oa1[r] * invA);
            dst[32 + ln] = f2bf(oa2[r] * invA);
            float invB = 1.0f / l4b[r];
            unsigned short* dstB = dst + (size_t)64 * CC;
            dstB[ln] = f2bf(ob0[r] * invB);
            dstB[16 + ln] = f2bf(ob1[r] * invB);
            dstB[32 + ln] = f2bf(ob2[r] * invB);
        }
    }
}

extern "C" void kernel_launch(void* const* d_in, const int* in_sizes, int n_in,
                              void* d_out, int out_size, void* d_ws, size_t ws_size,
                              hipStream_t stream) {
    const float* hs = (const float*)d_in[0];
    const float* amask = (const float*)d_in[1];
    const float* Wq = (const float*)d_in[2];
    const float* bq = (const float*)d_in[3];
    const float* Wk = (const float*)d_in[4];
    const float* bk = (const float*)d_in[5];
    const float* Wv = (const float*)d_in[6];
    const float* bv = (const float*)d_in[7];
    const float* Wo = (const float*)d_in[8];
    const float* bo = (const float*)d_in[9];

    const size_t NELEM = (size_t)BB * TT * CC;  // 6291456
    const size_t WELEM = (size_t)CC * CC;       // 589824
    unsigned short* hb  = (unsigned short*)d_ws;
    unsigned short* qbuf = hb + NELEM;
    unsigned short* kbuf = qbuf + NELEM;
    unsigned short* vtb = kbuf + NELEM;   // bf16 [B,H,D,T]
    unsigned short* ctxb = vtb + NELEM;
    unsigned short* wqb = ctxb + NELEM;   // wq/wk/wv contiguous = stacked [2304][768]
    unsigned short* wkb = wqb + WELEM;
    unsigned short* wvb = wkb + WELEM;
    unsigned short* wob = wvb + WELEM;
    float2* ropetab = (float2*)(wob + WELEM);  // [2048][24]

    // one fused setup launch: hs cast (6144 blocks) + 4 weight casts (2304)
    // + rope table (192) = 8640 blocks
    setup_all<<<8640, 256, 0, stream>>>(hs, hb, Wq, Wk, Wv, Wo,
                                        wqb, wkb, wvb, wob, ropetab);

    gemm_mfma<1><<<18 * 64, 256, 0, stream>>>(hb, wqb, bq, bk, bv, qbuf, kbuf, vtb);

    int rope_total = BB * TT * NHD * 3;  // 8 pairs per thread
    rope_bf<<<rope_total / 256, 256, 0, stream>>>(qbuf, kbuf, ropetab);

    attn_kernel<<<512, 256, 0, stream>>>(qbuf, kbuf, vtb, amask, ctxb);

    gemm_out<<<12 * 64, 256, 0, stream>>>(ctxb, wob, bo, (float*)d_out);
}